// Round 6
// baseline (76.741 us; speedup 1.0000x reference)
//
#include <hip/hip_runtime.h>

// Output: (1, 9, 16, 9, 256, 256) f32 — out[d][c][a][y][x]
// Input:  (1, 16, 9, 256, 256)  f32 — in[c][a][y][x]
// t = (d-4)*(a-4); out[d][c][a][y][x] = in[c][a][y-t][x-t] if in-bounds else 0.
//
// Scatter decomposition (round 3) + dwordx4 stores (round 5).
// Round 6: PLAIN stores (no nontemporal hint) — let L2 write-back do the
// DRAM write-combining, like the 7 TB/s rocclr fill kernel does.

#define RTILE 16

typedef float vf4 __attribute__((ext_vector_type(4)));

template<int TR>
__device__ __forceinline__ void emit_plane(const float* __restrict__ lds_t,
                                           float* __restrict__ oplane,
                                           int g0, int t, int tq,
                                           int tx, int ty)
{
    for (int yb = ty; yb < RTILE; yb += 4) {          // wave-uniform row
        int y = g0 + yb + t;
        if (y < 0 || y >= 256) continue;
        const float* __restrict__ lrow = lds_t + yb * 256;
        float* __restrict__ orow = oplane + (long)y * 256;

        int m2 = tx - tq;                 // aligned chunk indices
        int m2c = m2 < 0 ? 0 : (m2 > 63 ? 63 : m2);
        vf4 B = *reinterpret_cast<const vf4*>(lrow + 4 * m2c);
        float w0, w1, w2, w3;
        if (TR == 0) {
            w0 = B.x; w1 = B.y; w2 = B.z; w3 = B.w;
        } else {
            int m1 = m2 - 1;
            int m1c = m1 < 0 ? 0 : (m1 > 63 ? 63 : m1);
            vf4 A = *reinterpret_cast<const vf4*>(lrow + 4 * m1c);
            float cc[8] = {A.x, A.y, A.z, A.w, B.x, B.y, B.z, B.w};
            w0 = cc[4 - TR]; w1 = cc[5 - TR];         // compile-time indices
            w2 = cc[6 - TR]; w3 = cc[7 - TR];
        }
        int x0 = 4 * tx;
        int lo = t, hi = 256 + t;                     // valid x: [t, 256+t)
        vf4 v;
        v.x = (x0 + 0 >= lo && x0 + 0 < hi) ? w0 : 0.f;
        v.y = (x0 + 1 >= lo && x0 + 1 < hi) ? w1 : 0.f;
        v.z = (x0 + 2 >= lo && x0 + 2 < hi) ? w2 : 0.f;
        v.w = (x0 + 3 >= lo && x0 + 3 < hi) ? w3 : 0.f;
        *reinterpret_cast<vf4*>(orow + x0) = v;       // plain store (L2 write-back)
    }
}

__global__ __launch_bounds__(256) void cost_volume_kernel(
    const float* __restrict__ in, float* __restrict__ out)
{
    __shared__ float lds_t[RTILE * 256];   // 16 KB

    int ca = blockIdx.y;                    // c*9 + a
    int c = ca / 9;
    int a = ca - c * 9;
    int a4 = a - 4;
    int g0 = blockIdx.x * RTILE;            // first input row of tile

    int tx = threadIdx.x;                   // 0..63
    int ty = threadIdx.y;                   // 0..3

    // ---- stage 16 input rows, no halo ----
    const float* __restrict__ slice = in + (long)ca * 65536;
    #pragma unroll
    for (int r0 = 0; r0 < RTILE; r0 += 4) {
        int r = r0 + ty;
        *reinterpret_cast<vf4*>(&lds_t[r * 256 + tx * 4]) =
            *reinterpret_cast<const vf4*>(slice + (long)(g0 + r) * 256 + tx * 4);
    }
    __syncthreads();

    // ---- scatter to 9 d-shifted planes ----
    #pragma unroll
    for (int d = 0; d < 9; ++d) {
        int t = (d - 4) * a4;
        float* __restrict__ oplane = out + ((long)(d * 16 + c) * 9 + a) * 65536L;
        int tq = t >> 2;                    // arithmetic shift = floor div
        switch (t & 3) {
        case 0: emit_plane<0>(lds_t, oplane, g0, t, tq, tx, ty); break;
        case 1: emit_plane<1>(lds_t, oplane, g0, t, tq, tx, ty); break;
        case 2: emit_plane<2>(lds_t, oplane, g0, t, tq, tx, ty); break;
        case 3: emit_plane<3>(lds_t, oplane, g0, t, tq, tx, ty); break;
        }

        // ---- distributed zero-fill: block bi fills zero-row bi (if any) ----
        int zn = t < 0 ? -t : t;            // 0..16 uncovered rows per plane
        int z0 = t > 0 ? 0 : 256 + t;
        if (zn && ty == (d & 3) && (int)blockIdx.x < zn) {
            float* __restrict__ orow = oplane + (long)(z0 + (int)blockIdx.x) * 256;
            vf4 z = {0.f, 0.f, 0.f, 0.f};
            *reinterpret_cast<vf4*>(orow + tx * 4) = z;
        }
    }
}

extern "C" void kernel_launch(void* const* d_in, const int* in_sizes, int n_in,
                              void* d_out, int out_size, void* d_ws, size_t ws_size,
                              hipStream_t stream)
{
    const float* in = (const float*)d_in[0];
    float* out = (float*)d_out;

    dim3 block(64, 4, 1);    // 256 threads = 4 waves
    dim3 grid(16, 144, 1);   // 16 input y-tiles x (16 c * 9 a)
    cost_volume_kernel<<<grid, block, 0, stream>>>(in, out);
}

// Round 7
// 73.577 us; speedup vs baseline: 1.0430x; 1.0430x over previous
//
#include <hip/hip_runtime.h>

// Output: (1, 9, 16, 9, 256, 256) f32 — out[d][c][a][y][x]
// Input:  (1, 16, 9, 256, 256)  f32 — in[c][a][y][x]
// t = (d-4)*(a-4); out[d][c][a][y][x] = in[c][a][y-t][x-t] if in-bounds else 0.
//
// Scatter decomposition + dwordx4 NT stores (round 5, best) + round 7:
// RTILE=32 -> 1152 blocks, 32KB LDS, 5 blocks/CU resident -> whole grid
// co-resident in ONE dispatch wave (no low-occupancy tail).

#define RTILE 32

typedef float vf4 __attribute__((ext_vector_type(4)));

template<int TR>
__device__ __forceinline__ void emit_plane(const float* __restrict__ lds_t,
                                           float* __restrict__ oplane,
                                           int g0, int t, int tq,
                                           int tx, int ty)
{
    for (int yb = ty; yb < RTILE; yb += 4) {          // wave-uniform row
        int y = g0 + yb + t;
        if (y < 0 || y >= 256) continue;
        const float* __restrict__ lrow = lds_t + yb * 256;
        float* __restrict__ orow = oplane + (long)y * 256;

        int m2 = tx - tq;                 // aligned chunk indices
        int m2c = m2 < 0 ? 0 : (m2 > 63 ? 63 : m2);
        vf4 B = *reinterpret_cast<const vf4*>(lrow + 4 * m2c);
        float w0, w1, w2, w3;
        if (TR == 0) {
            w0 = B.x; w1 = B.y; w2 = B.z; w3 = B.w;
        } else {
            int m1 = m2 - 1;
            int m1c = m1 < 0 ? 0 : (m1 > 63 ? 63 : m1);
            vf4 A = *reinterpret_cast<const vf4*>(lrow + 4 * m1c);
            float cc[8] = {A.x, A.y, A.z, A.w, B.x, B.y, B.z, B.w};
            w0 = cc[4 - TR]; w1 = cc[5 - TR];         // compile-time indices
            w2 = cc[6 - TR]; w3 = cc[7 - TR];
        }
        int x0 = 4 * tx;
        int lo = t, hi = 256 + t;                     // valid x: [t, 256+t)
        vf4 v;
        v.x = (x0 + 0 >= lo && x0 + 0 < hi) ? w0 : 0.f;
        v.y = (x0 + 1 >= lo && x0 + 1 < hi) ? w1 : 0.f;
        v.z = (x0 + 2 >= lo && x0 + 2 < hi) ? w2 : 0.f;
        v.w = (x0 + 3 >= lo && x0 + 3 < hi) ? w3 : 0.f;
        __builtin_nontemporal_store(v, reinterpret_cast<vf4*>(orow + x0));
    }
}

__global__ __launch_bounds__(256) void cost_volume_kernel(
    const float* __restrict__ in, float* __restrict__ out)
{
    __shared__ float lds_t[RTILE * 256];   // 32 KB -> 5 blocks/CU

    int ca = blockIdx.y;                    // c*9 + a
    int c = ca / 9;
    int a = ca - c * 9;
    int a4 = a - 4;
    int bx = blockIdx.x;                    // 0..7
    int g0 = bx * RTILE;                    // first input row of tile

    int tx = threadIdx.x;                   // 0..63
    int ty = threadIdx.y;                   // 0..3

    // ---- stage 32 input rows, no halo ----
    const float* __restrict__ slice = in + (long)ca * 65536;
    #pragma unroll
    for (int r0 = 0; r0 < RTILE; r0 += 4) {
        int r = r0 + ty;
        *reinterpret_cast<vf4*>(&lds_t[r * 256 + tx * 4]) =
            *reinterpret_cast<const vf4*>(slice + (long)(g0 + r) * 256 + tx * 4);
    }
    __syncthreads();

    // ---- scatter to 9 d-shifted planes ----
    #pragma unroll
    for (int d = 0; d < 9; ++d) {
        int t = (d - 4) * a4;
        float* __restrict__ oplane = out + ((long)(d * 16 + c) * 9 + a) * 65536L;
        int tq = t >> 2;                    // arithmetic shift = floor div
        switch (t & 3) {
        case 0: emit_plane<0>(lds_t, oplane, g0, t, tq, tx, ty); break;
        case 1: emit_plane<1>(lds_t, oplane, g0, t, tq, tx, ty); break;
        case 2: emit_plane<2>(lds_t, oplane, g0, t, tq, tx, ty); break;
        case 3: emit_plane<3>(lds_t, oplane, g0, t, tq, tx, ty); break;
        }

        // ---- distributed zero-fill: 8 blocks x 2 waves cover up to 16 rows ----
        int zn = t < 0 ? -t : t;            // 0..16 uncovered rows per plane
        int z0 = t > 0 ? 0 : 256 + t;
        int zi = bx * 2 + ty;               // ty in {0,1} -> rows 0..15
        if (ty < 2 && zi < zn) {
            float* __restrict__ orow = oplane + (long)(z0 + zi) * 256;
            vf4 z = {0.f, 0.f, 0.f, 0.f};
            __builtin_nontemporal_store(z, reinterpret_cast<vf4*>(orow + tx * 4));
        }
    }
}

extern "C" void kernel_launch(void* const* d_in, const int* in_sizes, int n_in,
                              void* d_out, int out_size, void* d_ws, size_t ws_size,
                              hipStream_t stream)
{
    const float* in = (const float*)d_in[0];
    float* out = (float*)d_out;

    dim3 block(64, 4, 1);    // 256 threads = 4 waves
    dim3 grid(8, 144, 1);    // 8 input y-tiles x (16 c * 9 a) = 1152 blocks
    cost_volume_kernel<<<grid, block, 0, stream>>>(in, out);
}